// Round 1
// baseline (74.727 us; speedup 1.0000x reference)
//
#include <hip/hip_runtime.h>

#define CONF_THR 2.5f
#define NCLS 80

// 4 lanes cooperate per row: each lane reads 20 floats (5x float4) of the row,
// computes a partial max, group-of-4 shuffle max, then per-lane box contribution
// (boxes have exactly 4 coords -> one per lane, fully coalesced), wave sum,
// block sum, one atomicAdd per block.
__global__ __launch_bounds__(256) void yolov8_reduce_kernel(
    const float* __restrict__ post,
    const float* __restrict__ boxes,
    float* __restrict__ out, int n) {

    const int tid  = threadIdx.x;
    const int lane = tid & 63;
    const int wav  = tid >> 6;
    const int row  = blockIdx.x * 64 + (tid >> 2);
    const int q    = tid & 3;

    float m = -1e30f;
    if (row < n) {
        const float4* p = reinterpret_cast<const float4*>(
            post + (size_t)row * NCLS + q * 20);
        #pragma unroll
        for (int i = 0; i < 5; ++i) {
            float4 v = p[i];
            m = fmaxf(m, fmaxf(fmaxf(v.x, v.y), fmaxf(v.z, v.w)));
        }
    }
    // max across the 4-lane group (lanes differ only in bits 0..1)
    m = fmaxf(m, __shfl_xor(m, 1));
    m = fmaxf(m, __shfl_xor(m, 2));

    float c = 0.0f;
    if (row < n && m >= CONF_THR) {
        c = boxes[(size_t)row * 4 + q];   // lane q takes box coord q: coalesced
        if (q == 0) c += m;               // one lane per row adds the max score
    }

    // full-wave (64-lane) butterfly sum
    #pragma unroll
    for (int off = 1; off < 64; off <<= 1)
        c += __shfl_xor(c, off);

    __shared__ float ws[4];
    if (lane == 0) ws[wav] = c;
    __syncthreads();
    if (tid == 0) {
        atomicAdd(out, ws[0] + ws[1] + ws[2] + ws[3]);
    }
}

extern "C" void kernel_launch(void* const* d_in, const int* in_sizes, int n_in,
                              void* d_out, int out_size, void* d_ws, size_t ws_size,
                              hipStream_t stream) {
    const float* post  = (const float*)d_in[0];   // [N, 80] f32
    const float* boxes = (const float*)d_in[1];   // [N, 4]  f32
    float* out = (float*)d_out;                   // scalar f32

    const int n = in_sizes[0] / NCLS;             // 300000
    const int rows_per_block = 64;                // 256 threads / 4 lanes-per-row
    const int grid = (n + rows_per_block - 1) / rows_per_block;

    hipMemsetAsync(out, 0, sizeof(float), stream);
    yolov8_reduce_kernel<<<grid, 256, 0, stream>>>(post, boxes, out, n);
}

// Round 2
// 34.565 us; speedup vs baseline: 2.1620x; 2.1620x over previous
//
#include <hip/hip_runtime.h>

#define CONF_THR 2.5f
#define NCLS 80
#define BLOCK 256
#define ROWS_PER_BLOCK 256   // 4 iterations x 64 rows

// 4 lanes per row; each thread handles 4 rows (batched so all 24 loads are in
// flight before any dependent use). Box coords loaded unconditionally and
// concurrently with post loads -- mask applied in VALU, no second memory stall.
__global__ __launch_bounds__(BLOCK) void yolov8_reduce_kernel(
    const float* __restrict__ post,
    const float* __restrict__ boxes,
    float* __restrict__ out, int n) {

    const int tid  = threadIdx.x;
    const int lane = tid & 63;
    const int wav  = tid >> 6;
    const int q    = tid & 3;       // quarter-row / box-coord index
    const int sub  = tid >> 2;      // row-in-group 0..63

    const int base = blockIdx.x * ROWS_PER_BLOCK;

    float c = 0.0f;

    #pragma unroll
    for (int it = 0; it < 4; ++it) {
        const int row = base + it * 64 + sub;
        float m  = -1e30f;
        float bx = 0.0f;
        if (row < n) {
            const float4* p = reinterpret_cast<const float4*>(
                post + (size_t)row * NCLS + q * 20);
            float4 v0 = p[0], v1 = p[1], v2 = p[2], v3 = p[3], v4 = p[4];
            bx = boxes[(size_t)row * 4 + q];           // independent, in flight
            float m0 = fmaxf(fmaxf(v0.x, v0.y), fmaxf(v0.z, v0.w));
            float m1 = fmaxf(fmaxf(v1.x, v1.y), fmaxf(v1.z, v1.w));
            float m2 = fmaxf(fmaxf(v2.x, v2.y), fmaxf(v2.z, v2.w));
            float m3 = fmaxf(fmaxf(v3.x, v3.y), fmaxf(v3.z, v3.w));
            float m4 = fmaxf(fmaxf(v4.x, v4.y), fmaxf(v4.z, v4.w));
            m = fmaxf(fmaxf(fmaxf(m0, m1), fmaxf(m2, m3)), m4);
        }
        // max across the 4-lane group sharing this row
        m = fmaxf(m, __shfl_xor(m, 1));
        m = fmaxf(m, __shfl_xor(m, 2));
        if (m >= CONF_THR) c += bx + ((q == 0) ? m : 0.0f);
    }

    // 64-lane butterfly sum
    #pragma unroll
    for (int off = 1; off < 64; off <<= 1)
        c += __shfl_xor(c, off);

    __shared__ float ws[4];
    if (lane == 0) ws[wav] = c;
    __syncthreads();
    if (tid == 0) atomicAdd(out, ws[0] + ws[1] + ws[2] + ws[3]);
}

extern "C" void kernel_launch(void* const* d_in, const int* in_sizes, int n_in,
                              void* d_out, int out_size, void* d_ws, size_t ws_size,
                              hipStream_t stream) {
    const float* post  = (const float*)d_in[0];   // [N, 80] f32
    const float* boxes = (const float*)d_in[1];   // [N, 4]  f32
    float* out = (float*)d_out;                   // scalar f32

    const int n = in_sizes[0] / NCLS;             // 300000
    const int grid = (n + ROWS_PER_BLOCK - 1) / ROWS_PER_BLOCK;   // 1172

    hipMemsetAsync(out, 0, sizeof(float), stream);
    yolov8_reduce_kernel<<<grid, BLOCK, 0, stream>>>(post, boxes, out, n);
}

// Round 3
// 22.253 us; speedup vs baseline: 3.3581x; 1.5533x over previous
//
#include <hip/hip_runtime.h>

#define CONF_THR 2.5f
#define NCLS 80
#define BLOCK 256
#define ITERS 4
#define ROWS_PER_BLOCK (64 * ITERS)   // 256 rows per block

// Pass 1: 4 lanes per row, 4 rows per thread. ALL 24 loads issued in a pure
// load phase (explicit arrays, static indices -> registers), compute after.
// Per-block partial sum -> plain store to d_ws (no init / no atomics needed).
__global__ __launch_bounds__(BLOCK) void yolo_pass1(
    const float* __restrict__ post,
    const float* __restrict__ boxes,
    float* __restrict__ partial, int n) {

    const int tid  = threadIdx.x;
    const int lane = tid & 63;
    const int wav  = tid >> 6;
    const int q    = tid & 3;       // quarter-row / box-coord index
    const int sub  = tid >> 2;      // row-in-group 0..63
    const int base = blockIdx.x * ROWS_PER_BLOCK;

    float4 v[ITERS][5];
    float  bx[ITERS];

    // ---- load phase: everything independent, all in flight ----
    #pragma unroll
    for (int it = 0; it < ITERS; ++it) {
        const int row = base + it * 64 + sub;
        if (row < n) {
            const float4* p = reinterpret_cast<const float4*>(
                post + (size_t)row * NCLS + q * 20);
            v[it][0] = p[0]; v[it][1] = p[1]; v[it][2] = p[2];
            v[it][3] = p[3]; v[it][4] = p[4];
            bx[it] = boxes[(size_t)row * 4 + q];
        } else {
            const float4 ninf = make_float4(-1e30f, -1e30f, -1e30f, -1e30f);
            v[it][0] = ninf; v[it][1] = ninf; v[it][2] = ninf;
            v[it][3] = ninf; v[it][4] = ninf;
            bx[it] = 0.0f;
        }
    }

    // ---- compute phase ----
    float c = 0.0f;
    #pragma unroll
    for (int it = 0; it < ITERS; ++it) {
        float m0 = fmaxf(fmaxf(v[it][0].x, v[it][0].y), fmaxf(v[it][0].z, v[it][0].w));
        float m1 = fmaxf(fmaxf(v[it][1].x, v[it][1].y), fmaxf(v[it][1].z, v[it][1].w));
        float m2 = fmaxf(fmaxf(v[it][2].x, v[it][2].y), fmaxf(v[it][2].z, v[it][2].w));
        float m3 = fmaxf(fmaxf(v[it][3].x, v[it][3].y), fmaxf(v[it][3].z, v[it][3].w));
        float m4 = fmaxf(fmaxf(v[it][4].x, v[it][4].y), fmaxf(v[it][4].z, v[it][4].w));
        float m  = fmaxf(fmaxf(fmaxf(m0, m1), fmaxf(m2, m3)), m4);
        // max across the 4-lane group sharing this row
        m = fmaxf(m, __shfl_xor(m, 1));
        m = fmaxf(m, __shfl_xor(m, 2));
        if (m >= CONF_THR) c += bx[it] + ((q == 0) ? m : 0.0f);
    }

    // 64-lane butterfly sum
    #pragma unroll
    for (int off = 1; off < 64; off <<= 1)
        c += __shfl_xor(c, off);

    __shared__ float ws[4];
    if (lane == 0) ws[wav] = c;
    __syncthreads();
    if (tid == 0) partial[blockIdx.x] = ws[0] + ws[1] + ws[2] + ws[3];
}

// Pass 2: reduce nb per-block partials -> scalar. Plain store, deterministic.
__global__ __launch_bounds__(1024) void yolo_pass2(
    const float* __restrict__ partial, float* __restrict__ out, int nb) {

    const int tid  = threadIdx.x;
    const int lane = tid & 63;
    const int wav  = tid >> 6;

    float s = 0.0f;
    for (int i = tid; i < nb; i += 1024) s += partial[i];

    #pragma unroll
    for (int off = 1; off < 64; off <<= 1)
        s += __shfl_xor(s, off);

    __shared__ float ws[16];
    if (lane == 0) ws[wav] = s;
    __syncthreads();
    if (tid == 0) {
        float t = 0.0f;
        #pragma unroll
        for (int w = 0; w < 16; ++w) t += ws[w];
        out[0] = t;
    }
}

extern "C" void kernel_launch(void* const* d_in, const int* in_sizes, int n_in,
                              void* d_out, int out_size, void* d_ws, size_t ws_size,
                              hipStream_t stream) {
    const float* post  = (const float*)d_in[0];   // [N, 80] f32
    const float* boxes = (const float*)d_in[1];   // [N, 4]  f32
    float* out     = (float*)d_out;               // scalar f32
    float* partial = (float*)d_ws;                // nb floats of scratch

    const int n  = in_sizes[0] / NCLS;            // 300000
    const int nb = (n + ROWS_PER_BLOCK - 1) / ROWS_PER_BLOCK;   // 1172

    yolo_pass1<<<nb, BLOCK, 0, stream>>>(post, boxes, partial, n);
    yolo_pass2<<<1, 1024, 0, stream>>>(partial, out, nb);
}